// Round 1
// baseline (465.739 us; speedup 1.0000x reference)
//
#include <hip/hip_runtime.h>
#include <math.h>

#define NB 16
#define NN 16384
#define DD 128
#define KK 10

// ws layout (floats):
//   hsum : [2][NB][DD]      @0      4096   ([0]=H1 col sums, [1]=H2 col sums)
//   accg : [2][NB][40]      @4096   1280   ([k]=SE, [10+k]=Yx, [20+k]=Yy, [30+k]=Yz)
//   v    : [2][NB][KK][DD]  @5376   40960  (scale folded: 1/(N*sqrt(d)))
#define WS_FLOATS 46336

__device__ __forceinline__ float4 f4add(float4 a, float4 b) {
    return make_float4(a.x + b.x, a.y + b.y, a.z + b.z, a.w + b.w);
}

// ---------------------------------------------------------------------------
// Kernel 1: column sums of ONE tensor (used for H2 up-front).
// grid 4096 = 16 batches x 256 chunks of 64 rows. 256 threads.
// 8 independent float4 loads issued before any use -> 8 in flight per wave.
__global__ __launch_bounds__(256, 8) void k_sum(const float* __restrict__ H,
                                                float* __restrict__ dst) {
    int bi = blockIdx.x;
    int b = bi >> 8;
    int chunk = bi & 255;
    const float4* src4 = (const float4*)(H + ((size_t)b * NN + (size_t)chunk * 64) * DD);
    int tid = threadIdx.x;
    float4 x0 = src4[0 * 256 + tid];
    float4 x1 = src4[1 * 256 + tid];
    float4 x2 = src4[2 * 256 + tid];
    float4 x3 = src4[3 * 256 + tid];
    float4 x4 = src4[4 * 256 + tid];
    float4 x5 = src4[5 * 256 + tid];
    float4 x6 = src4[6 * 256 + tid];
    float4 x7 = src4[7 * 256 + tid];
    float4 a = f4add(f4add(f4add(x0, x1), f4add(x2, x3)),
                     f4add(f4add(x4, x5), f4add(x6, x7)));
    // lanes l and l^32 cover the same column group
    a.x += __shfl_xor(a.x, 32);
    a.y += __shfl_xor(a.y, 32);
    a.z += __shfl_xor(a.z, 32);
    a.w += __shfl_xor(a.w, 32);
    __shared__ float red[4][32][4];
    int wv = tid >> 6, lane = tid & 63;
    if (lane < 32) {
        red[wv][lane][0] = a.x; red[wv][lane][1] = a.y;
        red[wv][lane][2] = a.z; red[wv][lane][3] = a.w;
    }
    __syncthreads();
    if (tid < 32) {
        float t0 = 0.f, t1 = 0.f, t2 = 0.f, t3 = 0.f;
#pragma unroll
        for (int w = 0; w < 4; ++w) {
            t0 += red[w][tid][0]; t1 += red[w][tid][1];
            t2 += red[w][tid][2]; t3 += red[w][tid][3];
        }
        float* d = dst + (size_t)b * DD + tid * 4;
        atomicAdd(d + 0, t0);
        atomicAdd(d + 1, t1);
        atomicAdd(d + 2, t2);
        atomicAdd(d + 3, t3);
    }
}

// ---------------------------------------------------------------------------
// Kernel 2: vdst[b][k][d] = SCALE * sum_e W[k][d][e] * hsrc[b][e]
// grid 160 = 16 x 10, 128 threads (one per d).
__global__ __launch_bounds__(128) void k_v(const float* __restrict__ W,
                                           const float* __restrict__ hsrc,
                                           float* __restrict__ vdst) {
    int bi = blockIdx.x;
    int b = bi / 10;
    int k = bi % 10;
    const float* Wk = W + (size_t)k * DD * DD;
    const float* hb = hsrc + (size_t)b * DD;
    __shared__ float4 h_s[32];
    int tid = threadIdx.x;
    if (tid < 32) h_s[tid] = ((const float4*)hb)[tid];
    __syncthreads();
    const float4* Wrow = (const float4*)(Wk + (size_t)tid * DD);
    float acc = 0.f;
#pragma unroll 8
    for (int e4 = 0; e4 < 32; ++e4) {
        float4 w4 = Wrow[e4];
        float4 h4 = h_s[e4];
        acc += w4.x * h4.x + w4.y * h4.y + w4.z * h4.z + w4.w * h4.w;
    }
    const float SCALE = (float)(1.0 / (16384.0 * 11.313708498984761));  // 1/(N*sqrt(128))
    vdst[((size_t)b * KK + k) * DD + tid] = acc * SCALE;
}

// ---------------------------------------------------------------------------
// Kernel 3: scores + exp + weighted-X partial sums for ONE path.
// grid 2048 = 16 batches x 128 tiles of 128 rows. 256 threads.
// 8 lanes per row-group, 4 rows per group. FOLD=true additionally
// accumulates this tensor's column sums into hsum0 (saves a full pass).
template <bool FOLD>
__global__ __launch_bounds__(256, 4) void k_scores(const float* __restrict__ H,
                                                   const float* __restrict__ X,
                                                   const float* __restrict__ v,
                                                   float* __restrict__ accgp,
                                                   float* __restrict__ hsum0) {
    int bi = blockIdx.x;
    int b = bi >> 7;
    int tile = bi & 127;
    int row0 = tile << 7;
    const float* Hb = H + (size_t)b * NN * DD;
    const float* Xb = X + (size_t)b * NN * 3;
    const float* vp = v + (size_t)b * KK * DD;

    __shared__ float4 v_s4[KK * DD / 4];   // 1280 floats
    __shared__ float red[4][40];
    __shared__ float4 colred4[4][4][8];    // [wave][j][l], used only when FOLD

    int tid = threadIdx.x;
    for (int i = tid; i < KK * DD / 4; i += 256)
        v_s4[i] = ((const float4*)vp)[i];
    __syncthreads();

    int g = tid >> 3;       // group 0..31 (8 per wave), 4 rows each
    int l = tid & 7;        // lane within group -> d-slice
    int nbase = row0 + (g << 2);

    float accs[4][KK];
#pragma unroll
    for (int r = 0; r < 4; ++r)
#pragma unroll
        for (int k = 0; k < KK; ++k) accs[r][k] = 0.f;
    float4 csum[4];
    if (FOLD) {
#pragma unroll
        for (int j = 0; j < 4; ++j) csum[j] = make_float4(0.f, 0.f, 0.f, 0.f);
    }

#pragma unroll
    for (int j = 0; j < 4; ++j) {
        float4 h[4];
#pragma unroll
        for (int r = 0; r < 4; ++r)
            h[r] = *(const float4*)(Hb + (size_t)(nbase + r) * DD + (j << 5) + (l << 2));
        if (FOLD)
            csum[j] = f4add(csum[j], f4add(f4add(h[0], h[1]), f4add(h[2], h[3])));
#pragma unroll
        for (int k = 0; k < KK; ++k) {
            float4 vv = v_s4[k * 32 + (j << 3) + l];
#pragma unroll
            for (int r = 0; r < 4; ++r)
                accs[r][k] += h[r].x * vv.x + h[r].y * vv.y + h[r].z * vv.z + h[r].w * vv.w;
        }
    }
    // reduce the d-partials across the 8 lanes of each group (broadcast)
#pragma unroll
    for (int r = 0; r < 4; ++r)
#pragma unroll
        for (int k = 0; k < KK; ++k) {
            float s = accs[r][k];
            s += __shfl_xor(s, 1);
            s += __shfl_xor(s, 2);
            s += __shfl_xor(s, 4);
            accs[r][k] = s;
        }

    // Lane-split epilogue: lane l owns k=l (and k=l+8 when l<2).
    // Static-index select chain (no dynamic register indexing).
    float sk0[4], sk1[4];
#pragma unroll
    for (int r = 0; r < 4; ++r) {
        float u0 = 0.f, u1 = 0.f;
#pragma unroll
        for (int k = 0; k < KK; ++k) {
            if (k == l) u0 = accs[r][k];
            if (k == l + 8) u1 = accs[r][k];
        }
        sk0[r] = u0;
        sk1[r] = u1;
    }
    float m1 = (l < 2) ? 1.f : 0.f;
    float pse0 = 0.f, py00 = 0.f, py10 = 0.f, py20 = 0.f;
    float pse1 = 0.f, py01 = 0.f, py11 = 0.f, py21 = 0.f;
    // |s| <~ 0.3, so exp without max-subtraction is exact softmax semantics.
#pragma unroll
    for (int r = 0; r < 4; ++r) {
        int n = nbase + r;
        float x0 = Xb[(size_t)n * 3 + 0];
        float x1 = Xb[(size_t)n * 3 + 1];
        float x2 = Xb[(size_t)n * 3 + 2];
        float e0 = __expf(sk0[r]);
        float e1 = m1 * __expf(sk1[r]);
        pse0 += e0; py00 += e0 * x0; py10 += e0 * x1; py20 += e0 * x2;
        pse1 += e1; py01 += e1 * x0; py11 += e1 * x1; py21 += e1 * x2;
    }
    // reduce across the 8 groups of the wave (xor 8/16/32 preserves l -> k identity)
#pragma unroll
    for (int d = 8; d <= 32; d <<= 1) {
        pse0 += __shfl_xor(pse0, d); py00 += __shfl_xor(py00, d);
        py10 += __shfl_xor(py10, d); py20 += __shfl_xor(py20, d);
        pse1 += __shfl_xor(pse1, d); py01 += __shfl_xor(py01, d);
        py11 += __shfl_xor(py11, d); py21 += __shfl_xor(py21, d);
    }
    if (FOLD) {
#pragma unroll
        for (int j = 0; j < 4; ++j) {
#pragma unroll
            for (int d = 8; d <= 32; d <<= 1) {
                csum[j].x += __shfl_xor(csum[j].x, d);
                csum[j].y += __shfl_xor(csum[j].y, d);
                csum[j].z += __shfl_xor(csum[j].z, d);
                csum[j].w += __shfl_xor(csum[j].w, d);
            }
        }
    }
    int wv = tid >> 6, lane = tid & 63;
    if (lane < 8) {
        red[wv][l] = pse0;
        red[wv][10 + l] = py00;
        red[wv][20 + l] = py10;
        red[wv][30 + l] = py20;
        if (l < 2) {
            red[wv][8 + l] = pse1;
            red[wv][18 + l] = py01;
            red[wv][28 + l] = py11;
            red[wv][38 + l] = py21;
        }
        if (FOLD) {
#pragma unroll
            for (int j = 0; j < 4; ++j) colred4[wv][j][l] = csum[j];
        }
    }
    __syncthreads();
    if (tid < 40) {
        float s = red[0][tid] + red[1][tid] + red[2][tid] + red[3][tid];
        atomicAdd(accgp + (size_t)b * 40 + tid, s);
    }
    if (FOLD && tid < 128) {
        // col index == tid: tid = j*32 + l*4 + c
        int j = tid >> 5, rr = tid & 31, ll = rr >> 2, c = rr & 3;
        float s = 0.f;
#pragma unroll
        for (int w = 0; w < 4; ++w) s += ((const float*)&colred4[w][j][ll])[c];
        atomicAdd(hsum0 + (size_t)b * DD + tid, s);
    }
}

// ---------------------------------------------------------------------------
// Kernel 4: finalize Y1/Y2 and Kabsch alignment (fp64 one-sided Jacobi SVD).
// grid 16 (one per batch), 64 threads.
__global__ __launch_bounds__(64) void k_final(const float* __restrict__ accg,
                                              float* __restrict__ out) {
    int b = blockIdx.x;
    int tid = threadIdx.x;
    __shared__ float Ys[2][KK][3];
    if (tid < 2 * KK * 3) {
        int p = tid / 30;
        int r = tid % 30;
        int k = r / 3;
        int c = r % 3;
        const float* a = accg + (size_t)(p * NB + b) * 40;
        float val = a[10 + c * 10 + k] / a[k];
        Ys[p][k][c] = val;
        out[((size_t)(b * 3 + p) * KK + k) * 3 + c] = val;
    }
    __syncthreads();
    if (tid == 0) {
        double P[KK][3], Q[KK][3];
        double c1[3] = {0, 0, 0}, c2[3] = {0, 0, 0};
        for (int i = 0; i < KK; ++i)
            for (int c = 0; c < 3; ++c) {
                P[i][c] = (double)Ys[0][i][c];
                Q[i][c] = (double)Ys[1][i][c];
                c1[c] += P[i][c];
                c2[c] += Q[i][c];
            }
        for (int c = 0; c < 3; ++c) { c1[c] /= KK; c2[c] /= KK; }
        double A0[3][3];
        for (int a = 0; a < 3; ++a)
            for (int c = 0; c < 3; ++c) {
                double s = 0;
                for (int i = 0; i < KK; ++i) s += (P[i][a] - c1[a]) * (Q[i][c] - c2[c]);
                A0[a][c] = s;
            }
        double Bm[3][3], V[3][3];
        for (int a = 0; a < 3; ++a)
            for (int c = 0; c < 3; ++c) { Bm[a][c] = A0[a][c]; V[a][c] = (a == c) ? 1.0 : 0.0; }
        for (int sweep = 0; sweep < 16; ++sweep)
            for (int p = 0; p < 2; ++p)
                for (int q = p + 1; q < 3; ++q) {
                    double al = 0, be = 0, ga = 0;
                    for (int r = 0; r < 3; ++r) {
                        al += Bm[r][p] * Bm[r][p];
                        be += Bm[r][q] * Bm[r][q];
                        ga += Bm[r][p] * Bm[r][q];
                    }
                    if (fabs(ga) < 1e-300) continue;
                    double zeta = (be - al) / (2.0 * ga);
                    double t = copysign(1.0, zeta) / (fabs(zeta) + sqrt(1.0 + zeta * zeta));
                    double cs = 1.0 / sqrt(1.0 + t * t);
                    double sn = cs * t;
                    for (int r = 0; r < 3; ++r) {
                        double bp = Bm[r][p], bq = Bm[r][q];
                        Bm[r][p] = cs * bp - sn * bq;
                        Bm[r][q] = sn * bp + cs * bq;
                        double vp = V[r][p], vq = V[r][q];
                        V[r][p] = cs * vp - sn * vq;
                        V[r][q] = sn * vp + cs * vq;
                    }
                }
        double sig[3];
        for (int j = 0; j < 3; ++j) {
            sig[j] = sqrt(Bm[0][j] * Bm[0][j] + Bm[1][j] * Bm[1][j] + Bm[2][j] * Bm[2][j]);
            if (sig[j] < 1e-300) sig[j] = 1e-300;
        }
        int jmin = 0;
        if (sig[1] < sig[jmin]) jmin = 1;
        if (sig[2] < sig[jmin]) jmin = 2;
        double det = A0[0][0] * (A0[1][1] * A0[2][2] - A0[1][2] * A0[2][1])
                   - A0[0][1] * (A0[1][0] * A0[2][2] - A0[1][2] * A0[2][0])
                   + A0[0][2] * (A0[1][0] * A0[2][1] - A0[1][1] * A0[2][0]);
        double sgn = (det >= 0.0) ? 1.0 : -1.0;
        double R[3][3];
        for (int a = 0; a < 3; ++a)
            for (int c = 0; c < 3; ++c) {
                double s = 0;
                for (int j = 0; j < 3; ++j) {
                    double dj = (j == jmin) ? sgn : 1.0;
                    s += dj * (Bm[a][j] / sig[j]) * V[c][j];
                }
                R[a][c] = s;
            }
        for (int i = 0; i < KK; ++i)
            for (int c = 0; c < 3; ++c) {
                double s = c2[c];
                for (int a = 0; a < 3; ++a) s += (P[i][a] - c1[a]) * R[a][c];
                out[((size_t)(b * 3 + 2) * KK + i) * 3 + c] = (float)s;
            }
    }
}

// ---------------------------------------------------------------------------
// Pipeline (3 passes over 128-MiB tensors instead of 4):
//   sum(H2) -> v1 -> scores1(H1, fold sum(H1)) -> v2 -> scores2(H2) -> final
extern "C" void kernel_launch(void* const* d_in, const int* in_sizes, int n_in,
                              void* d_out, int out_size, void* d_ws, size_t ws_size,
                              hipStream_t stream) {
    const float* H1 = (const float*)d_in[0];
    const float* H2 = (const float*)d_in[1];
    const float* X1 = (const float*)d_in[2];
    const float* X2 = (const float*)d_in[3];
    const float* W1 = (const float*)d_in[4];
    const float* W2 = (const float*)d_in[5];
    float* out = (float*)d_out;
    float* ws = (float*)d_ws;
    float* hsum = ws;                  // [2][NB][DD]: [0]=H1 sums, [1]=H2 sums
    float* accg = ws + 4096;           // [2][NB][40]
    float* v    = ws + 5376;           // [2][NB][KK][DD]

    hipMemsetAsync(d_ws, 0, 5376 * sizeof(float), stream);
    hipLaunchKernelGGL(k_sum, dim3(4096), dim3(256), 0, stream, H2, hsum + (size_t)NB * DD);
    hipLaunchKernelGGL(k_v, dim3(160), dim3(128), 0, stream, W1, hsum + (size_t)NB * DD, v);
    hipLaunchKernelGGL((k_scores<true>), dim3(2048), dim3(256), 0, stream,
                       H1, X1, v, accg, hsum);
    hipLaunchKernelGGL(k_v, dim3(160), dim3(128), 0, stream, W2, hsum,
                       v + (size_t)NB * KK * DD);
    hipLaunchKernelGGL((k_scores<false>), dim3(2048), dim3(256), 0, stream,
                       H2, X2, v + (size_t)NB * KK * DD, accg + (size_t)NB * 40,
                       (float*)nullptr);
    hipLaunchKernelGGL(k_final, dim3(16), dim3(64), 0, stream, accg, out);
}

// Round 2
// 392.070 us; speedup vs baseline: 1.1879x; 1.1879x over previous
//
#include <hip/hip_runtime.h>
#include <math.h>

#define NB 16
#define NN 16384
#define DD 128
#define KK 10

// ws layout (floats):
//   hsum : [2][NB][DD]      @0      4096   ([0]=H1 col sums, [1]=H2 col sums)
//   accg : [2][NB][40]      @4096   1280   ([k]=SE, [10+k]=Yx, [20+k]=Yy, [30+k]=Yz)
//   v    : [2][NB][KK][DD]  @5376   40960  (scale folded: 1/(N*sqrt(d)))
#define WS_FLOATS 46336

__device__ __forceinline__ float4 f4add(float4 a, float4 b) {
    return make_float4(a.x + b.x, a.y + b.y, a.z + b.z, a.w + b.w);
}

// ---------------------------------------------------------------------------
// Kernel 1: column sums of ONE tensor (used for H2 up-front).
// grid 4096 = 16 batches x 256 chunks of 64 rows. 256 threads.
// 8 independent float4 loads in flight per wave. VGPR ~45 < 64 cap -> no spill.
__global__ __launch_bounds__(256, 8) void k_sum(const float* __restrict__ H,
                                                float* __restrict__ dst) {
    int bi = blockIdx.x;
    int b = bi >> 8;
    int chunk = bi & 255;
    const float4* src4 = (const float4*)(H + ((size_t)b * NN + (size_t)chunk * 64) * DD);
    int tid = threadIdx.x;
    float4 x0 = src4[0 * 256 + tid];
    float4 x1 = src4[1 * 256 + tid];
    float4 x2 = src4[2 * 256 + tid];
    float4 x3 = src4[3 * 256 + tid];
    float4 x4 = src4[4 * 256 + tid];
    float4 x5 = src4[5 * 256 + tid];
    float4 x6 = src4[6 * 256 + tid];
    float4 x7 = src4[7 * 256 + tid];
    float4 a = f4add(f4add(f4add(x0, x1), f4add(x2, x3)),
                     f4add(f4add(x4, x5), f4add(x6, x7)));
    // lanes l and l^32 cover the same column group
    a.x += __shfl_xor(a.x, 32);
    a.y += __shfl_xor(a.y, 32);
    a.z += __shfl_xor(a.z, 32);
    a.w += __shfl_xor(a.w, 32);
    __shared__ float red[4][32][4];
    int wv = tid >> 6, lane = tid & 63;
    if (lane < 32) {
        red[wv][lane][0] = a.x; red[wv][lane][1] = a.y;
        red[wv][lane][2] = a.z; red[wv][lane][3] = a.w;
    }
    __syncthreads();
    if (tid < 32) {
        float t0 = 0.f, t1 = 0.f, t2 = 0.f, t3 = 0.f;
#pragma unroll
        for (int w = 0; w < 4; ++w) {
            t0 += red[w][tid][0]; t1 += red[w][tid][1];
            t2 += red[w][tid][2]; t3 += red[w][tid][3];
        }
        float* d = dst + (size_t)b * DD + tid * 4;
        atomicAdd(d + 0, t0);
        atomicAdd(d + 1, t1);
        atomicAdd(d + 2, t2);
        atomicAdd(d + 3, t3);
    }
}

// ---------------------------------------------------------------------------
// Kernel 2: vdst[b][k][d] = SCALE * sum_e W[k][d][e] * hsrc[b][e]
// grid 160 = 16 x 10, 128 threads (one per d).
__global__ __launch_bounds__(128) void k_v(const float* __restrict__ W,
                                           const float* __restrict__ hsrc,
                                           float* __restrict__ vdst) {
    int bi = blockIdx.x;
    int b = bi / 10;
    int k = bi % 10;
    const float* Wk = W + (size_t)k * DD * DD;
    const float* hb = hsrc + (size_t)b * DD;
    __shared__ float4 h_s[32];
    int tid = threadIdx.x;
    if (tid < 32) h_s[tid] = ((const float4*)hb)[tid];
    __syncthreads();
    const float4* Wrow = (const float4*)(Wk + (size_t)tid * DD);
    float acc = 0.f;
#pragma unroll 8
    for (int e4 = 0; e4 < 32; ++e4) {
        float4 w4 = Wrow[e4];
        float4 h4 = h_s[e4];
        acc += w4.x * h4.x + w4.y * h4.y + w4.z * h4.z + w4.w * h4.w;
    }
    const float SCALE = (float)(1.0 / (16384.0 * 11.313708498984761));  // 1/(N*sqrt(128))
    vdst[((size_t)b * KK + k) * DD + tid] = acc * SCALE;
}

// ---------------------------------------------------------------------------
// Kernel 3: scores + exp + weighted-X partial sums for ONE path.
// grid 2048 = 16 batches x 128 tiles of 128 rows. 256 threads.
// 16 lanes per row-group, 2 rows per group, 4 sweeps of 32 rows.
// accs = 2x10 regs (was 4x10: the round-1 spill source). Plain launch_bounds:
// NO min-waves cap (the (256,4) cap forced VGPR=64 -> 253 MB scratch writes).
// Next sweep's loads are software-prefetched so HBM latency hides under FMA.
template <bool FOLD>
__global__ __launch_bounds__(256) void k_scores(const float* __restrict__ H,
                                                const float* __restrict__ X,
                                                const float* __restrict__ v,
                                                float* __restrict__ accgp,
                                                float* __restrict__ hsum0) {
    int bi = blockIdx.x;
    int b = bi >> 7;
    int tile = bi & 127;
    int row0 = tile << 7;
    const float* Hb = H + (size_t)b * NN * DD;
    const float* Xb = X + (size_t)b * NN * 3;
    const float* vp = v + (size_t)b * KK * DD;

    __shared__ float4 v_s4[KK * DD / 4];   // 320 float4 = 5 KB
    __shared__ float red[4][40];
    __shared__ float4 colred4[4][2][16];   // [wave][j][l], FOLD only

    int tid = threadIdx.x;
    for (int i = tid; i < KK * DD / 4; i += 256)
        v_s4[i] = ((const float4*)vp)[i];
    __syncthreads();

    int g = tid >> 4;       // group 0..15 (4 per wave), 2 rows each
    int l = tid & 15;       // lane within group -> d-slice (cols l*4 and 64+l*4)
    float kmask = (l < KK) ? 1.f : 0.f;

    float pse = 0.f, py0 = 0.f, py1 = 0.f, py2 = 0.f;   // lane owns k = l
    float4 cs0 = make_float4(0.f, 0.f, 0.f, 0.f);       // col sums (FOLD)
    float4 cs1 = make_float4(0.f, 0.f, 0.f, 0.f);

    // sweep 0 loads
    int n0 = row0 + g * 2;
    const float* hp = Hb + (size_t)n0 * DD + (l << 2);
    float4 h00 = *(const float4*)(hp);
    float4 h01 = *(const float4*)(hp + 64);
    float4 h10 = *(const float4*)(hp + DD);
    float4 h11 = *(const float4*)(hp + DD + 64);
    float xa0 = Xb[(size_t)n0 * 3 + 0];
    float xa1 = Xb[(size_t)n0 * 3 + 1];
    float xa2 = Xb[(size_t)n0 * 3 + 2];
    float xb0 = Xb[(size_t)n0 * 3 + 3];
    float xb1 = Xb[(size_t)n0 * 3 + 4];
    float xb2 = Xb[(size_t)n0 * 3 + 5];

#pragma unroll
    for (int sweep = 0; sweep < 4; ++sweep) {
        // prefetch next sweep (rows advance by 32)
        float4 p00, p01, p10, p11;
        float qa0, qa1, qa2, qb0, qb1, qb2;
        if (sweep < 3) {
            const float* hpn = hp + (size_t)(sweep + 1) * 32 * DD;
            p00 = *(const float4*)(hpn);
            p01 = *(const float4*)(hpn + 64);
            p10 = *(const float4*)(hpn + DD);
            p11 = *(const float4*)(hpn + DD + 64);
            size_t xn = (size_t)(n0 + (sweep + 1) * 32) * 3;
            qa0 = Xb[xn + 0]; qa1 = Xb[xn + 1]; qa2 = Xb[xn + 2];
            qb0 = Xb[xn + 3]; qb1 = Xb[xn + 4]; qb2 = Xb[xn + 5];
        }
        if (FOLD) {
            cs0 = f4add(cs0, f4add(h00, h10));
            cs1 = f4add(cs1, f4add(h01, h11));
        }
        float acc0[KK], acc1[KK];
#pragma unroll
        for (int k = 0; k < KK; ++k) {
            float4 v0 = v_s4[k * 32 + l];
            float4 v1 = v_s4[k * 32 + 16 + l];
            acc0[k] = h00.x * v0.x + h00.y * v0.y + h00.z * v0.z + h00.w * v0.w
                    + h01.x * v1.x + h01.y * v1.y + h01.z * v1.z + h01.w * v1.w;
            acc1[k] = h10.x * v0.x + h10.y * v0.y + h10.z * v0.z + h10.w * v0.w
                    + h11.x * v1.x + h11.y * v1.y + h11.z * v1.z + h11.w * v1.w;
        }
        // reduce the d-partials across the 16 lanes of the group (broadcast)
#pragma unroll
        for (int k = 0; k < KK; ++k) {
            float s0 = acc0[k], s1 = acc1[k];
            s0 += __shfl_xor(s0, 1); s0 += __shfl_xor(s0, 2);
            s0 += __shfl_xor(s0, 4); s0 += __shfl_xor(s0, 8);
            s1 += __shfl_xor(s1, 1); s1 += __shfl_xor(s1, 2);
            s1 += __shfl_xor(s1, 4); s1 += __shfl_xor(s1, 8);
            acc0[k] = s0; acc1[k] = s1;
        }
        // lane-split: lane l takes k = l (static-index select chain)
        float u0 = 0.f, u1 = 0.f;
#pragma unroll
        for (int k = 0; k < KK; ++k) {
            if (k == l) { u0 = acc0[k]; u1 = acc1[k]; }
        }
        // |s| <~ 0.3, so exp without max-subtraction is exact softmax semantics.
        float e0 = kmask * __expf(u0);
        float e1 = kmask * __expf(u1);
        pse += e0 + e1;
        py0 += e0 * xa0 + e1 * xb0;
        py1 += e0 * xa1 + e1 * xb1;
        py2 += e0 * xa2 + e1 * xb2;
        if (sweep < 3) {
            h00 = p00; h01 = p01; h10 = p10; h11 = p11;
            xa0 = qa0; xa1 = qa1; xa2 = qa2;
            xb0 = qb0; xb1 = qb1; xb2 = qb2;
        }
    }
    // reduce across the 4 groups of the wave (xor 16/32 preserves l -> k identity)
    pse += __shfl_xor(pse, 16); pse += __shfl_xor(pse, 32);
    py0 += __shfl_xor(py0, 16); py0 += __shfl_xor(py0, 32);
    py1 += __shfl_xor(py1, 16); py1 += __shfl_xor(py1, 32);
    py2 += __shfl_xor(py2, 16); py2 += __shfl_xor(py2, 32);
    if (FOLD) {
        cs0.x += __shfl_xor(cs0.x, 16); cs0.x += __shfl_xor(cs0.x, 32);
        cs0.y += __shfl_xor(cs0.y, 16); cs0.y += __shfl_xor(cs0.y, 32);
        cs0.z += __shfl_xor(cs0.z, 16); cs0.z += __shfl_xor(cs0.z, 32);
        cs0.w += __shfl_xor(cs0.w, 16); cs0.w += __shfl_xor(cs0.w, 32);
        cs1.x += __shfl_xor(cs1.x, 16); cs1.x += __shfl_xor(cs1.x, 32);
        cs1.y += __shfl_xor(cs1.y, 16); cs1.y += __shfl_xor(cs1.y, 32);
        cs1.z += __shfl_xor(cs1.z, 16); cs1.z += __shfl_xor(cs1.z, 32);
        cs1.w += __shfl_xor(cs1.w, 16); cs1.w += __shfl_xor(cs1.w, 32);
    }
    int wv = tid >> 6, lane = tid & 63;
    if (lane < 16) {
        if (lane < KK) {
            red[wv][lane] = pse;
            red[wv][10 + lane] = py0;
            red[wv][20 + lane] = py1;
            red[wv][30 + lane] = py2;
        }
        if (FOLD) {
            colred4[wv][0][lane] = cs0;
            colred4[wv][1][lane] = cs1;
        }
    }
    __syncthreads();
    if (tid < 40) {
        float s = red[0][tid] + red[1][tid] + red[2][tid] + red[3][tid];
        atomicAdd(accgp + (size_t)b * 40 + tid, s);
    }
    if (FOLD && tid < 128) {
        // col == tid: j = tid>>6, ll = (tid&63)>>2, c = tid&3
        int j = tid >> 6, cc = tid & 63, ll = cc >> 2, c = cc & 3;
        float s = 0.f;
#pragma unroll
        for (int w = 0; w < 4; ++w) s += ((const float*)&colred4[w][j][ll])[c];
        atomicAdd(hsum0 + (size_t)b * DD + tid, s);
    }
}

// ---------------------------------------------------------------------------
// Kernel 4: finalize Y1/Y2 and Kabsch alignment (fp64 one-sided Jacobi SVD).
// grid 16 (one per batch), 64 threads.
__global__ __launch_bounds__(64) void k_final(const float* __restrict__ accg,
                                              float* __restrict__ out) {
    int b = blockIdx.x;
    int tid = threadIdx.x;
    __shared__ float Ys[2][KK][3];
    if (tid < 2 * KK * 3) {
        int p = tid / 30;
        int r = tid % 30;
        int k = r / 3;
        int c = r % 3;
        const float* a = accg + (size_t)(p * NB + b) * 40;
        float val = a[10 + c * 10 + k] / a[k];
        Ys[p][k][c] = val;
        out[((size_t)(b * 3 + p) * KK + k) * 3 + c] = val;
    }
    __syncthreads();
    if (tid == 0) {
        double P[KK][3], Q[KK][3];
        double c1[3] = {0, 0, 0}, c2[3] = {0, 0, 0};
        for (int i = 0; i < KK; ++i)
            for (int c = 0; c < 3; ++c) {
                P[i][c] = (double)Ys[0][i][c];
                Q[i][c] = (double)Ys[1][i][c];
                c1[c] += P[i][c];
                c2[c] += Q[i][c];
            }
        for (int c = 0; c < 3; ++c) { c1[c] /= KK; c2[c] /= KK; }
        double A0[3][3];
        for (int a = 0; a < 3; ++a)
            for (int c = 0; c < 3; ++c) {
                double s = 0;
                for (int i = 0; i < KK; ++i) s += (P[i][a] - c1[a]) * (Q[i][c] - c2[c]);
                A0[a][c] = s;
            }
        double Bm[3][3], V[3][3];
        for (int a = 0; a < 3; ++a)
            for (int c = 0; c < 3; ++c) { Bm[a][c] = A0[a][c]; V[a][c] = (a == c) ? 1.0 : 0.0; }
        for (int sweep = 0; sweep < 16; ++sweep)
            for (int p = 0; p < 2; ++p)
                for (int q = p + 1; q < 3; ++q) {
                    double al = 0, be = 0, ga = 0;
                    for (int r = 0; r < 3; ++r) {
                        al += Bm[r][p] * Bm[r][p];
                        be += Bm[r][q] * Bm[r][q];
                        ga += Bm[r][p] * Bm[r][q];
                    }
                    if (fabs(ga) < 1e-300) continue;
                    double zeta = (be - al) / (2.0 * ga);
                    double t = copysign(1.0, zeta) / (fabs(zeta) + sqrt(1.0 + zeta * zeta));
                    double cs = 1.0 / sqrt(1.0 + t * t);
                    double sn = cs * t;
                    for (int r = 0; r < 3; ++r) {
                        double bp = Bm[r][p], bq = Bm[r][q];
                        Bm[r][p] = cs * bp - sn * bq;
                        Bm[r][q] = sn * bp + cs * bq;
                        double vp = V[r][p], vq = V[r][q];
                        V[r][p] = cs * vp - sn * vq;
                        V[r][q] = sn * vp + cs * vq;
                    }
                }
        double sig[3];
        for (int j = 0; j < 3; ++j) {
            sig[j] = sqrt(Bm[0][j] * Bm[0][j] + Bm[1][j] * Bm[1][j] + Bm[2][j] * Bm[2][j]);
            if (sig[j] < 1e-300) sig[j] = 1e-300;
        }
        int jmin = 0;
        if (sig[1] < sig[jmin]) jmin = 1;
        if (sig[2] < sig[jmin]) jmin = 2;
        double det = A0[0][0] * (A0[1][1] * A0[2][2] - A0[1][2] * A0[2][1])
                   - A0[0][1] * (A0[1][0] * A0[2][2] - A0[1][2] * A0[2][0])
                   + A0[0][2] * (A0[1][0] * A0[2][1] - A0[1][1] * A0[2][0]);
        double sgn = (det >= 0.0) ? 1.0 : -1.0;
        double R[3][3];
        for (int a = 0; a < 3; ++a)
            for (int c = 0; c < 3; ++c) {
                double s = 0;
                for (int j = 0; j < 3; ++j) {
                    double dj = (j == jmin) ? sgn : 1.0;
                    s += dj * (Bm[a][j] / sig[j]) * V[c][j];
                }
                R[a][c] = s;
            }
        for (int i = 0; i < KK; ++i)
            for (int c = 0; c < 3; ++c) {
                double s = c2[c];
                for (int a = 0; a < 3; ++a) s += (P[i][a] - c1[a]) * R[a][c];
                out[((size_t)(b * 3 + 2) * KK + i) * 3 + c] = (float)s;
            }
    }
}

// ---------------------------------------------------------------------------
// Pipeline (3 passes over 128-MiB tensors instead of 4):
//   sum(H2) -> v1 -> scores1(H1, fold sum(H1)) -> v2 -> scores2(H2) -> final
extern "C" void kernel_launch(void* const* d_in, const int* in_sizes, int n_in,
                              void* d_out, int out_size, void* d_ws, size_t ws_size,
                              hipStream_t stream) {
    const float* H1 = (const float*)d_in[0];
    const float* H2 = (const float*)d_in[1];
    const float* X1 = (const float*)d_in[2];
    const float* X2 = (const float*)d_in[3];
    const float* W1 = (const float*)d_in[4];
    const float* W2 = (const float*)d_in[5];
    float* out = (float*)d_out;
    float* ws = (float*)d_ws;
    float* hsum = ws;                  // [2][NB][DD]: [0]=H1 sums, [1]=H2 sums
    float* accg = ws + 4096;           // [2][NB][40]
    float* v    = ws + 5376;           // [2][NB][KK][DD]

    hipMemsetAsync(d_ws, 0, 5376 * sizeof(float), stream);
    hipLaunchKernelGGL(k_sum, dim3(4096), dim3(256), 0, stream, H2, hsum + (size_t)NB * DD);
    hipLaunchKernelGGL(k_v, dim3(160), dim3(128), 0, stream, W1, hsum + (size_t)NB * DD, v);
    hipLaunchKernelGGL((k_scores<true>), dim3(2048), dim3(256), 0, stream,
                       H1, X1, v, accg, hsum);
    hipLaunchKernelGGL(k_v, dim3(160), dim3(128), 0, stream, W2, hsum,
                       v + (size_t)NB * KK * DD);
    hipLaunchKernelGGL((k_scores<false>), dim3(2048), dim3(256), 0, stream,
                       H2, X2, v + (size_t)NB * KK * DD, accg + (size_t)NB * 40,
                       (float*)nullptr);
    hipLaunchKernelGGL(k_final, dim3(16), dim3(64), 0, stream, accg, out);
}

// Round 3
// 367.425 us; speedup vs baseline: 1.2676x; 1.0671x over previous
//
#include <hip/hip_runtime.h>
#include <math.h>

#define NB 16
#define NN 16384
#define DD 128
#define KK 10
#define NCHUNK 128   // row-chunks per (tensor,batch) for partial column sums
#define NTILE 128    // row-tiles per (path,batch) for score partials

// ws layout (floats) — every word we read is written first; no zero-init, no atomics:
//   hpart: [2][NB][NCHUNK][DD]  @0        524288   (col-sum partials, t=0 H1, t=1 H2)
//   v    : [2][NB][KK][DD]      @524288   40960    (scale folded: 1/(N*sqrt(d)))
//   spart: [2][NB][NTILE][40]   @565248   163840   (per-tile SE/Yx/Yy/Yz partials)

__device__ __forceinline__ float4 f4add(float4 a, float4 b) {
    return make_float4(a.x + b.x, a.y + b.y, a.z + b.z, a.w + b.w);
}

// ---------------------------------------------------------------------------
// Split-butterfly reduction: 10 per-lane partials across a 16-lane group.
// Entry: a[k] = this lane's partial for score k (k=0..9); slots 10..15 == 0.
// Exit:  lane l (l<10) returns sum over the 16 lanes of a[l].
// 15 shuffles total (vs 40 for naive per-k butterflies).
__device__ __forceinline__ float kreduce16(const float a[KK], int l) {
    const bool h8 = (l & 8) != 0;
    const bool h4 = (l & 4) != 0;
    const bool h2 = (l & 2) != 0;
    const bool h1 = (l & 1) != 0;
    float b[8];
#pragma unroll
    for (int i = 0; i < 8; ++i) {
        float give = h8 ? a[i] : ((i < 2) ? a[i + 8] : 0.f);
        float r = __shfl_xor(give, 8);
        float keep = h8 ? ((i < 2) ? a[i + 8] : 0.f) : a[i];
        b[i] = keep + r;
    }
    float c[4];
#pragma unroll
    for (int i = 0; i < 4; ++i) {
        float give = h4 ? c[0] * 0.f + b[i] : b[i + 4];   // h4 ? b[i] : b[i+4]
        give = h4 ? b[i] : b[i + 4];
        float r = __shfl_xor(give, 4);
        float keep = h4 ? b[i + 4] : b[i];
        c[i] = keep + r;
    }
    float d2[2];
#pragma unroll
    for (int i = 0; i < 2; ++i) {
        float give = h2 ? c[i] : c[i + 2];
        float r = __shfl_xor(give, 2);
        float keep = h2 ? c[i + 2] : c[i];
        d2[i] = keep + r;
    }
    float give = h1 ? d2[0] : d2[1];
    float r = __shfl_xor(give, 1);
    float keep = h1 ? d2[1] : d2[0];
    return keep + r;
}

// ---------------------------------------------------------------------------
// Kernel 1: column-sum partials of BOTH tensors.
// grid 4096 = 2 tensors x 16 batches x 128 chunks of 128 rows. 256 threads.
// 8 loads in flight per batch, 2 batches; per-chunk result stored directly
// to a disjoint hpart slot (no atomics -> no contention, no zero-init).
__global__ __launch_bounds__(256, 8) void k_sums(const float* __restrict__ H1,
                                                 const float* __restrict__ H2,
                                                 float* __restrict__ hpart) {
    int bi = blockIdx.x;
    int t = bi >> 11;
    int rem = bi & 2047;
    int b = rem >> 7;
    int chunk = rem & 127;
    const float4* src4 = (const float4*)((t ? H2 : H1)
                         + ((size_t)b * NN + (size_t)chunk * 128) * DD);
    int tid = threadIdx.x;
    float4 s = make_float4(0.f, 0.f, 0.f, 0.f);
#pragma unroll
    for (int o = 0; o < 2; ++o) {
        const float4* base = src4 + o * 2048;
        float4 x0 = base[0 * 256 + tid];
        float4 x1 = base[1 * 256 + tid];
        float4 x2 = base[2 * 256 + tid];
        float4 x3 = base[3 * 256 + tid];
        float4 x4 = base[4 * 256 + tid];
        float4 x5 = base[5 * 256 + tid];
        float4 x6 = base[6 * 256 + tid];
        float4 x7 = base[7 * 256 + tid];
        s = f4add(s, f4add(f4add(f4add(x0, x1), f4add(x2, x3)),
                           f4add(f4add(x4, x5), f4add(x6, x7))));
    }
    // lanes l and l^32 cover the same column group
    s.x += __shfl_xor(s.x, 32);
    s.y += __shfl_xor(s.y, 32);
    s.z += __shfl_xor(s.z, 32);
    s.w += __shfl_xor(s.w, 32);
    __shared__ float red[4][32][4];
    int wv = tid >> 6, lane = tid & 63;
    if (lane < 32) {
        red[wv][lane][0] = s.x; red[wv][lane][1] = s.y;
        red[wv][lane][2] = s.z; red[wv][lane][3] = s.w;
    }
    __syncthreads();
    if (tid < 32) {
        float t0 = 0.f, t1 = 0.f, t2 = 0.f, t3 = 0.f;
#pragma unroll
        for (int w = 0; w < 4; ++w) {
            t0 += red[w][tid][0]; t1 += red[w][tid][1];
            t2 += red[w][tid][2]; t3 += red[w][tid][3];
        }
        *(float4*)(hpart + ((size_t)(t * NB + b) * NCHUNK + chunk) * DD + tid * 4)
            = make_float4(t0, t1, t2, t3);
    }
}

// ---------------------------------------------------------------------------
// Kernel 2: v[p][b][k][d] = SCALE * sum_e W[k][d][e] * hsum[srct][b][e]
// where hsum is reduced from hpart in the prologue (64 KB of L2 reads/block).
// grid 320 = 2 x 16 x 10, 128 threads (one per d).
__global__ __launch_bounds__(128) void k_v(const float* __restrict__ W1,
                                           const float* __restrict__ W2,
                                           const float* __restrict__ hpart,
                                           float* __restrict__ v) {
    int bi = blockIdx.x;
    int p = bi / 160;
    int rem = bi % 160;
    int b = rem / 10;
    int k = rem % 10;
    const float* W = (p ? W2 : W1) + (size_t)k * DD * DD;
    int srct = 1 - p;  // path1 uses mean(H2), path2 mean(H1)
    __shared__ __align__(16) float hs[DD];
    int tid = threadIdx.x;
    const float* hp = hpart + (size_t)(srct * NB + b) * NCHUNK * DD + tid;
    float s = 0.f;
#pragma unroll 8
    for (int c = 0; c < NCHUNK; ++c) s += hp[(size_t)c * DD];
    hs[tid] = s;
    __syncthreads();
    const float4* Wrow = (const float4*)(W + (size_t)tid * DD);
    const float4* h4p = (const float4*)hs;
    float acc = 0.f;
#pragma unroll 8
    for (int e4 = 0; e4 < 32; ++e4) {
        float4 w4 = Wrow[e4];
        float4 h4 = h4p[e4];
        acc += w4.x * h4.x + w4.y * h4.y + w4.z * h4.z + w4.w * h4.w;
    }
    const float SCALE = (float)(1.0 / (16384.0 * 11.313708498984761));  // 1/(N*sqrt(128))
    v[((size_t)(p * NB + b) * KK + k) * DD + tid] = acc * SCALE;
}

// ---------------------------------------------------------------------------
// Kernel 3: scores + exp + weighted-X partial sums, BOTH paths in one launch.
// grid 4096 = 2 paths x 16 batches x 128 tiles of 128 rows. 256 threads.
// 16 lanes per row-group, 2 rows per group, 4 sweeps of 32 rows.
// Plain launch_bounds (the (256,4) cap caused the round-1 spill disaster).
// Results stored to disjoint spart slots (no atomics).
__global__ __launch_bounds__(256) void k_scores(const float* __restrict__ H1,
                                                const float* __restrict__ H2,
                                                const float* __restrict__ X1,
                                                const float* __restrict__ X2,
                                                const float* __restrict__ v,
                                                float* __restrict__ spart) {
    int bi = blockIdx.x;
    int p = bi >> 11;
    int rem = bi & 2047;
    int b = rem >> 7;
    int tile = rem & 127;
    int row0 = tile << 7;
    const float* Hb = (p ? H2 : H1) + (size_t)b * NN * DD;
    const float* Xb = (p ? X2 : X1) + (size_t)b * NN * 3;
    const float* vp = v + (size_t)(p * NB + b) * KK * DD;

    __shared__ float4 v_s4[KK * DD / 4];   // 320 float4 = 5 KB
    __shared__ float red[4][40];

    int tid = threadIdx.x;
    for (int i = tid; i < KK * DD / 4; i += 256)
        v_s4[i] = ((const float4*)vp)[i];
    __syncthreads();

    int g = tid >> 4;       // group 0..15 (4 per wave), 2 rows each
    int l = tid & 15;       // lane within group -> d-slice (cols l*4 and 64+l*4)
    float kmask = (l < KK) ? 1.f : 0.f;

    float pse = 0.f, py0 = 0.f, py1 = 0.f, py2 = 0.f;   // lane owns k = l

    // sweep 0 loads
    int n0 = row0 + g * 2;
    const float* hp = Hb + (size_t)n0 * DD + (l << 2);
    float4 h00 = *(const float4*)(hp);
    float4 h01 = *(const float4*)(hp + 64);
    float4 h10 = *(const float4*)(hp + DD);
    float4 h11 = *(const float4*)(hp + DD + 64);
    float xa0 = Xb[(size_t)n0 * 3 + 0];
    float xa1 = Xb[(size_t)n0 * 3 + 1];
    float xa2 = Xb[(size_t)n0 * 3 + 2];
    float xb0 = Xb[(size_t)n0 * 3 + 3];
    float xb1 = Xb[(size_t)n0 * 3 + 4];
    float xb2 = Xb[(size_t)n0 * 3 + 5];

#pragma unroll
    for (int sweep = 0; sweep < 4; ++sweep) {
        // prefetch next sweep (rows advance by 32)
        float4 p00, p01, p10, p11;
        float qa0, qa1, qa2, qb0, qb1, qb2;
        if (sweep < 3) {
            const float* hpn = hp + (size_t)(sweep + 1) * 32 * DD;
            p00 = *(const float4*)(hpn);
            p01 = *(const float4*)(hpn + 64);
            p10 = *(const float4*)(hpn + DD);
            p11 = *(const float4*)(hpn + DD + 64);
            size_t xn = (size_t)(n0 + (sweep + 1) * 32) * 3;
            qa0 = Xb[xn + 0]; qa1 = Xb[xn + 1]; qa2 = Xb[xn + 2];
            qb0 = Xb[xn + 3]; qb1 = Xb[xn + 4]; qb2 = Xb[xn + 5];
        }
        float acc0[KK], acc1[KK];
#pragma unroll
        for (int k = 0; k < KK; ++k) {
            float4 v0 = v_s4[k * 32 + l];
            float4 v1 = v_s4[k * 32 + 16 + l];
            acc0[k] = h00.x * v0.x + h00.y * v0.y + h00.z * v0.z + h00.w * v0.w
                    + h01.x * v1.x + h01.y * v1.y + h01.z * v1.z + h01.w * v1.w;
            acc1[k] = h10.x * v0.x + h10.y * v0.y + h10.z * v0.z + h10.w * v0.w
                    + h11.x * v1.x + h11.y * v1.y + h11.z * v1.z + h11.w * v1.w;
        }
        // split-butterfly: lane l ends with the full group sum for k = l
        float s0 = kreduce16(acc0, l);
        float s1 = kreduce16(acc1, l);
        // |s| <~ 0.3, so exp without max-subtraction is exact softmax semantics.
        float e0 = kmask * __expf(s0);
        float e1 = kmask * __expf(s1);
        pse += e0 + e1;
        py0 += e0 * xa0 + e1 * xb0;
        py1 += e0 * xa1 + e1 * xb1;
        py2 += e0 * xa2 + e1 * xb2;
        if (sweep < 3) {
            h00 = p00; h01 = p01; h10 = p10; h11 = p11;
            xa0 = qa0; xa1 = qa1; xa2 = qa2;
            xb0 = qb0; xb1 = qb1; xb2 = qb2;
        }
    }
    // reduce across the 4 groups of the wave (xor 16/32 preserves l -> k identity)
    pse += __shfl_xor(pse, 16); pse += __shfl_xor(pse, 32);
    py0 += __shfl_xor(py0, 16); py0 += __shfl_xor(py0, 32);
    py1 += __shfl_xor(py1, 16); py1 += __shfl_xor(py1, 32);
    py2 += __shfl_xor(py2, 16); py2 += __shfl_xor(py2, 32);
    int wv = tid >> 6, lane = tid & 63;
    if (lane < KK) {
        red[wv][lane] = pse;
        red[wv][10 + lane] = py0;
        red[wv][20 + lane] = py1;
        red[wv][30 + lane] = py2;
    }
    __syncthreads();
    if (tid < 40) {
        float s = red[0][tid] + red[1][tid] + red[2][tid] + red[3][tid];
        spart[((size_t)(p * NB + b) * NTILE + tile) * 40 + tid] = s;
    }
}

// ---------------------------------------------------------------------------
// Kernel 4: reduce spart partials, finalize Y1/Y2, Kabsch (fp64 Jacobi SVD).
// grid 16 (one per batch), 128 threads.
__global__ __launch_bounds__(128) void k_final(const float* __restrict__ spart,
                                               float* __restrict__ out) {
    int b = blockIdx.x;
    int tid = threadIdx.x;
    __shared__ float acc[2][40];
    if (tid < 80) {
        int p = tid / 40, j = tid % 40;
        const float* sp = spart + (size_t)(p * NB + b) * NTILE * 40 + j;
        float s = 0.f;
        for (int tile = 0; tile < NTILE; ++tile) s += sp[(size_t)tile * 40];
        acc[p][j] = s;
    }
    __syncthreads();
    __shared__ float Ys[2][KK][3];
    if (tid < 2 * KK * 3) {
        int p = tid / 30;
        int r = tid % 30;
        int k = r / 3;
        int c = r % 3;
        float val = acc[p][10 + c * 10 + k] / acc[p][k];
        Ys[p][k][c] = val;
        out[((size_t)(b * 3 + p) * KK + k) * 3 + c] = val;
    }
    __syncthreads();
    if (tid == 0) {
        double P[KK][3], Q[KK][3];
        double c1[3] = {0, 0, 0}, c2[3] = {0, 0, 0};
        for (int i = 0; i < KK; ++i)
            for (int c = 0; c < 3; ++c) {
                P[i][c] = (double)Ys[0][i][c];
                Q[i][c] = (double)Ys[1][i][c];
                c1[c] += P[i][c];
                c2[c] += Q[i][c];
            }
        for (int c = 0; c < 3; ++c) { c1[c] /= KK; c2[c] /= KK; }
        double A0[3][3];
        for (int a = 0; a < 3; ++a)
            for (int c = 0; c < 3; ++c) {
                double s = 0;
                for (int i = 0; i < KK; ++i) s += (P[i][a] - c1[a]) * (Q[i][c] - c2[c]);
                A0[a][c] = s;
            }
        double Bm[3][3], V[3][3];
        for (int a = 0; a < 3; ++a)
            for (int c = 0; c < 3; ++c) { Bm[a][c] = A0[a][c]; V[a][c] = (a == c) ? 1.0 : 0.0; }
        for (int sweep = 0; sweep < 16; ++sweep)
            for (int p = 0; p < 2; ++p)
                for (int q = p + 1; q < 3; ++q) {
                    double al = 0, be = 0, ga = 0;
                    for (int r = 0; r < 3; ++r) {
                        al += Bm[r][p] * Bm[r][p];
                        be += Bm[r][q] * Bm[r][q];
                        ga += Bm[r][p] * Bm[r][q];
                    }
                    if (fabs(ga) < 1e-300) continue;
                    double zeta = (be - al) / (2.0 * ga);
                    double t = copysign(1.0, zeta) / (fabs(zeta) + sqrt(1.0 + zeta * zeta));
                    double cs = 1.0 / sqrt(1.0 + t * t);
                    double sn = cs * t;
                    for (int r = 0; r < 3; ++r) {
                        double bp = Bm[r][p], bq = Bm[r][q];
                        Bm[r][p] = cs * bp - sn * bq;
                        Bm[r][q] = sn * bp + cs * bq;
                        double vp = V[r][p], vq = V[r][q];
                        V[r][p] = cs * vp - sn * vq;
                        V[r][q] = sn * vp + cs * vq;
                    }
                }
        double sig[3];
        for (int j = 0; j < 3; ++j) {
            sig[j] = sqrt(Bm[0][j] * Bm[0][j] + Bm[1][j] * Bm[1][j] + Bm[2][j] * Bm[2][j]);
            if (sig[j] < 1e-300) sig[j] = 1e-300;
        }
        int jmin = 0;
        if (sig[1] < sig[jmin]) jmin = 1;
        if (sig[2] < sig[jmin]) jmin = 2;
        double det = A0[0][0] * (A0[1][1] * A0[2][2] - A0[1][2] * A0[2][1])
                   - A0[0][1] * (A0[1][0] * A0[2][2] - A0[1][2] * A0[2][0])
                   + A0[0][2] * (A0[1][0] * A0[2][1] - A0[1][1] * A0[2][0]);
        double sgn = (det >= 0.0) ? 1.0 : -1.0;
        double R[3][3];
        for (int a = 0; a < 3; ++a)
            for (int c = 0; c < 3; ++c) {
                double s = 0;
                for (int j = 0; j < 3; ++j) {
                    double dj = (j == jmin) ? sgn : 1.0;
                    s += dj * (Bm[a][j] / sig[j]) * V[c][j];
                }
                R[a][c] = s;
            }
        for (int i = 0; i < KK; ++i)
            for (int c = 0; c < 3; ++c) {
                double s = c2[c];
                for (int a = 0; a < 3; ++a) s += (P[i][a] - c1[a]) * R[a][c];
                out[((size_t)(b * 3 + 2) * KK + i) * 3 + c] = (float)s;
            }
    }
}

// ---------------------------------------------------------------------------
// Pipeline: 2 streaming passes. Pass 1 sums both tensors (268 MB HBM);
// pass 2 scores both (mostly L3: H1+H2 = 256 MiB ~= LLC). 4 launches,
// no memset, no atomics.
extern "C" void kernel_launch(void* const* d_in, const int* in_sizes, int n_in,
                              void* d_out, int out_size, void* d_ws, size_t ws_size,
                              hipStream_t stream) {
    const float* H1 = (const float*)d_in[0];
    const float* H2 = (const float*)d_in[1];
    const float* X1 = (const float*)d_in[2];
    const float* X2 = (const float*)d_in[3];
    const float* W1 = (const float*)d_in[4];
    const float* W2 = (const float*)d_in[5];
    float* out = (float*)d_out;
    float* ws = (float*)d_ws;
    float* hpart = ws;                   // 524288 floats
    float* v     = ws + 524288;          // 40960 floats
    float* spart = ws + 565248;          // 163840 floats

    hipLaunchKernelGGL(k_sums,   dim3(4096), dim3(256), 0, stream, H1, H2, hpart);
    hipLaunchKernelGGL(k_v,      dim3(320),  dim3(128), 0, stream, W1, W2, hpart, v);
    hipLaunchKernelGGL(k_scores, dim3(4096), dim3(256), 0, stream, H1, H2, X1, X2, v, spart);
    hipLaunchKernelGGL(k_final,  dim3(16),   dim3(128), 0, stream, spart, out);
}

// Round 5
// 355.223 us; speedup vs baseline: 1.3111x; 1.0344x over previous
//
#include <hip/hip_runtime.h>
#include <math.h>

#define NB 16
#define NN 16384
#define DD 128
#define KK 10
#define NT 128   // row-tiles (128 rows each) per batch

// ws layout (floats) — every word read is written first; no zero-init, no atomics:
//   hpart2 [NB][NT][DD]   @0        262144   (H2 column-sum partials)
//   hpart1 [NB][NT][DD]   @262144   262144   (H1 column-sum partials, from fold)
//   v1     [NB][KK][DD]   @524288   20480    (scale folded: 1/(N*sqrt(d)))
//   v2     [NB][KK][DD]   @544768   20480
//   spart  [2][NB][NT][40]@565248   163840   (per-tile SE/Yx/Yy/Yz partials)

__device__ __forceinline__ float4 f4add(float4 a, float4 b) {
    return make_float4(a.x + b.x, a.y + b.y, a.z + b.z, a.w + b.w);
}

// Split-butterfly reduction: 10 per-lane partials across a 16-lane group.
// Exit: lane l (l<10) holds the 16-lane sum of a[l]. 15 shuffles (vs 40 naive).
// HW-verified in round 3 (absmax 0).
__device__ __forceinline__ float kreduce16(const float a[KK], int l) {
    const bool h8 = (l & 8) != 0;
    const bool h4 = (l & 4) != 0;
    const bool h2 = (l & 2) != 0;
    const bool h1 = (l & 1) != 0;
    float b[8];
#pragma unroll
    for (int i = 0; i < 8; ++i) {
        float hi = (i < 2) ? a[i + 8] : 0.f;
        float give = h8 ? a[i] : hi;
        float keep = h8 ? hi : a[i];
        b[i] = keep + __shfl_xor(give, 8);
    }
    float c[4];
#pragma unroll
    for (int i = 0; i < 4; ++i) {
        float give = h4 ? b[i] : b[i + 4];
        float keep = h4 ? b[i + 4] : b[i];
        c[i] = keep + __shfl_xor(give, 4);
    }
    float d2[2];
#pragma unroll
    for (int i = 0; i < 2; ++i) {
        float give = h2 ? c[i] : c[i + 2];
        float keep = h2 ? c[i + 2] : c[i];
        d2[i] = keep + __shfl_xor(give, 2);
    }
    float give = h1 ? d2[0] : d2[1];
    float keep = h1 ? d2[1] : d2[0];
    return keep + __shfl_xor(give, 1);
}

// ---------------------------------------------------------------------------
// Kernel 1: column-sum partials of H2 only (H1's sum is folded into scores1).
// grid 2048 = 16 batches x 128 chunks of 128 rows. 256 threads.
// 16 NAMED float4 loads issued before any use -> 16 outstanding per wave
// (round 3's VGPR=32 proved the compiler kept only ~4 in flight).
__global__ __launch_bounds__(256) void k_sum(const float* __restrict__ H,
                                             float* __restrict__ hpart) {
    int bi = blockIdx.x;
    int b = bi >> 7;
    int chunk = bi & 127;
    const float4* src4 = (const float4*)(H + ((size_t)b * NN + (size_t)chunk * 128) * DD);
    int tid = threadIdx.x;
    float4 x[16];
#pragma unroll
    for (int j = 0; j < 16; ++j) x[j] = src4[j * 256 + tid];
    float4 t0 = f4add(x[0], x[1]),   t1 = f4add(x[2], x[3]);
    float4 t2 = f4add(x[4], x[5]),   t3 = f4add(x[6], x[7]);
    float4 t4 = f4add(x[8], x[9]),   t5 = f4add(x[10], x[11]);
    float4 t6 = f4add(x[12], x[13]), t7 = f4add(x[14], x[15]);
    float4 s = f4add(f4add(f4add(t0, t1), f4add(t2, t3)),
                     f4add(f4add(t4, t5), f4add(t6, t7)));
    // lanes l and l^32 cover the same column group (f4 col = (j*256+tid)%32)
    s.x += __shfl_xor(s.x, 32);
    s.y += __shfl_xor(s.y, 32);
    s.z += __shfl_xor(s.z, 32);
    s.w += __shfl_xor(s.w, 32);
    __shared__ float red[4][32][4];
    int wv = tid >> 6, lane = tid & 63;
    if (lane < 32) {
        red[wv][lane][0] = s.x; red[wv][lane][1] = s.y;
        red[wv][lane][2] = s.z; red[wv][lane][3] = s.w;
    }
    __syncthreads();
    if (tid < 32) {
        float t0s = 0.f, t1s = 0.f, t2s = 0.f, t3s = 0.f;
#pragma unroll
        for (int w = 0; w < 4; ++w) {
            t0s += red[w][tid][0]; t1s += red[w][tid][1];
            t2s += red[w][tid][2]; t3s += red[w][tid][3];
        }
        *(float4*)(hpart + ((size_t)b * NT + chunk) * DD + tid * 4)
            = make_float4(t0s, t1s, t2s, t3s);
    }
}

// ---------------------------------------------------------------------------
// Kernel 2: vdst[b][k][d] = SCALE * sum_e W[k][d][e] * (sum over hpart chunks)[b][e]
// grid 160 = 16 x 10, 128 threads (one per d). Chunk reduce is L2-resident.
__global__ __launch_bounds__(128) void k_v(const float* __restrict__ W,
                                           const float* __restrict__ hpart,
                                           float* __restrict__ vdst) {
    int bi = blockIdx.x;
    int b = bi / 10;
    int k = bi % 10;
    const float* Wk = W + (size_t)k * DD * DD;
    __shared__ __align__(16) float hs[DD];
    int tid = threadIdx.x;
    const float* hp = hpart + (size_t)b * NT * DD + tid;
    float s = 0.f;
#pragma unroll 8
    for (int c = 0; c < NT; ++c) s += hp[(size_t)c * DD];
    hs[tid] = s;
    __syncthreads();
    const float4* Wrow = (const float4*)(Wk + (size_t)tid * DD);
    const float4* h4p = (const float4*)hs;
    float acc = 0.f;
#pragma unroll 8
    for (int e4 = 0; e4 < 32; ++e4) {
        float4 w4 = Wrow[e4];
        float4 h4 = h4p[e4];
        acc += w4.x * h4.x + w4.y * h4.y + w4.z * h4.z + w4.w * h4.w;
    }
    const float SCALE = (float)(1.0 / (16384.0 * 11.313708498984761));  // 1/(N*sqrt(128))
    vdst[((size_t)b * KK + k) * DD + tid] = acc * SCALE;
}

// ---------------------------------------------------------------------------
// Kernel 3: scores + exp + weighted-X partial sums for ONE path.
// grid 2048 = 16 batches x 128 tiles of 128 rows. 256 threads.
// 16 lanes per row-group, 2 rows per group, 4 sweeps of 32 rows (HW-verified
// structure from round 3). FOLD additionally accumulates this tensor's
// column sums into hpartdst (per-tile disjoint slots, no atomics).
// Plain launch_bounds: the (256,4) cap caused the round-1 spill disaster.
template <bool FOLD>
__global__ __launch_bounds__(256) void k_scores(const float* __restrict__ Hsrc,
                                                const float* __restrict__ Xsrc,
                                                const float* __restrict__ vsrc,
                                                float* __restrict__ spartp,
                                                float* __restrict__ hpartdst) {
    int bi = blockIdx.x;
    int b = bi >> 7;
    int tile = bi & 127;
    int row0 = tile << 7;
    const float* Hb = Hsrc + (size_t)b * NN * DD;
    const float* Xb = Xsrc + (size_t)b * NN * 3;
    const float* vp = vsrc + (size_t)b * KK * DD;

    __shared__ float4 v_s4[KK * DD / 4];   // 320 float4 = 5 KB
    __shared__ float red[4][40];
    __shared__ float4 colred4[4][2][16];   // 2 KB, FOLD only

    int tid = threadIdx.x;
    for (int i = tid; i < KK * DD / 4; i += 256)
        v_s4[i] = ((const float4*)vp)[i];
    __syncthreads();

    int g = tid >> 4;       // group 0..15 (4 per wave), 2 rows each
    int l = tid & 15;       // lane within group -> d-slice (cols l*4 and 64+l*4)
    float kmask = (l < KK) ? 1.f : 0.f;

    float pse = 0.f, py0 = 0.f, py1 = 0.f, py2 = 0.f;   // lane owns k = l
    float4 cs0 = make_float4(0.f, 0.f, 0.f, 0.f);       // col sums (FOLD)
    float4 cs1 = make_float4(0.f, 0.f, 0.f, 0.f);

    // sweep 0 loads
    int n0 = row0 + g * 2;
    const float* hp = Hb + (size_t)n0 * DD + (l << 2);
    float4 h00 = *(const float4*)(hp);
    float4 h01 = *(const float4*)(hp + 64);
    float4 h10 = *(const float4*)(hp + DD);
    float4 h11 = *(const float4*)(hp + DD + 64);
    float xa0 = Xb[(size_t)n0 * 3 + 0];
    float xa1 = Xb[(size_t)n0 * 3 + 1];
    float xa2 = Xb[(size_t)n0 * 3 + 2];
    float xb0 = Xb[(size_t)n0 * 3 + 3];
    float xb1 = Xb[(size_t)n0 * 3 + 4];
    float xb2 = Xb[(size_t)n0 * 3 + 5];

#pragma unroll
    for (int sweep = 0; sweep < 4; ++sweep) {
        // prefetch next sweep (rows advance by 32)
        float4 p00, p01, p10, p11;
        float qa0, qa1, qa2, qb0, qb1, qb2;
        if (sweep < 3) {
            const float* hpn = hp + (size_t)(sweep + 1) * 32 * DD;
            p00 = *(const float4*)(hpn);
            p01 = *(const float4*)(hpn + 64);
            p10 = *(const float4*)(hpn + DD);
            p11 = *(const float4*)(hpn + DD + 64);
            size_t xn = (size_t)(n0 + (sweep + 1) * 32) * 3;
            qa0 = Xb[xn + 0]; qa1 = Xb[xn + 1]; qa2 = Xb[xn + 2];
            qb0 = Xb[xn + 3]; qb1 = Xb[xn + 4]; qb2 = Xb[xn + 5];
        }
        if (FOLD) {
            cs0 = f4add(cs0, f4add(h00, h10));
            cs1 = f4add(cs1, f4add(h01, h11));
        }
        float acc0[KK], acc1[KK];
#pragma unroll
        for (int k = 0; k < KK; ++k) {
            float4 v0 = v_s4[k * 32 + l];
            float4 v1 = v_s4[k * 32 + 16 + l];
            acc0[k] = h00.x * v0.x + h00.y * v0.y + h00.z * v0.z + h00.w * v0.w
                    + h01.x * v1.x + h01.y * v1.y + h01.z * v1.z + h01.w * v1.w;
            acc1[k] = h10.x * v0.x + h10.y * v0.y + h10.z * v0.z + h10.w * v0.w
                    + h11.x * v1.x + h11.y * v1.y + h11.z * v1.z + h11.w * v1.w;
        }
        // split-butterfly: lane l ends with the full group sum for k = l
        float s0 = kreduce16(acc0, l);
        float s1 = kreduce16(acc1, l);
        // |s| <~ 0.3 -> exp without max-subtraction is exact softmax semantics.
        float e0 = kmask * __expf(s0);
        float e1 = kmask * __expf(s1);
        pse += e0 + e1;
        py0 += e0 * xa0 + e1 * xb0;
        py1 += e0 * xa1 + e1 * xb1;
        py2 += e0 * xa2 + e1 * xb2;
        if (sweep < 3) {
            h00 = p00; h01 = p01; h10 = p10; h11 = p11;
            xa0 = qa0; xa1 = qa1; xa2 = qa2;
            xb0 = qb0; xb1 = qb1; xb2 = qb2;
        }
    }
    // reduce across the 4 groups of the wave (xor 16/32 preserves l -> k identity)
    pse += __shfl_xor(pse, 16); pse += __shfl_xor(pse, 32);
    py0 += __shfl_xor(py0, 16); py0 += __shfl_xor(py0, 32);
    py1 += __shfl_xor(py1, 16); py1 += __shfl_xor(py1, 32);
    py2 += __shfl_xor(py2, 16); py2 += __shfl_xor(py2, 32);
    if (FOLD) {
        cs0.x += __shfl_xor(cs0.x, 16); cs0.x += __shfl_xor(cs0.x, 32);
        cs0.y += __shfl_xor(cs0.y, 16); cs0.y += __shfl_xor(cs0.y, 32);
        cs0.z += __shfl_xor(cs0.z, 16); cs0.z += __shfl_xor(cs0.z, 32);
        cs0.w += __shfl_xor(cs0.w, 16); cs0.w += __shfl_xor(cs0.w, 32);
        cs1.x += __shfl_xor(cs1.x, 16); cs1.x += __shfl_xor(cs1.x, 32);
        cs1.y += __shfl_xor(cs1.y, 16); cs1.y += __shfl_xor(cs1.y, 32);
        cs1.z += __shfl_xor(cs1.z, 16); cs1.z += __shfl_xor(cs1.z, 32);
        cs1.w += __shfl_xor(cs1.w, 16); cs1.w += __shfl_xor(cs1.w, 32);
    }
    int wv = tid >> 6, lane = tid & 63;
    if (lane < 16) {
        if (lane < KK) {
            red[wv][lane] = pse;
            red[wv][10 + lane] = py0;
            red[wv][20 + lane] = py1;
            red[wv][30 + lane] = py2;
        }
        if (FOLD) {
            // cs0 on lane l covers cols [4l,4l+4); cs1 covers [64+4l, 64+4l+4)
            colred4[wv][0][lane] = cs0;
            colred4[wv][1][lane] = cs1;
        }
    }
    __syncthreads();
    if (tid < 40) {
        float s = red[0][tid] + red[1][tid] + red[2][tid] + red[3][tid];
        spartp[((size_t)b * NT + tile) * 40 + tid] = s;
    }
    if (FOLD && tid < DD) {
        // col == tid: j = tid>>6 selects cs0/cs1, ll = (tid&63)>>2, c = tid&3
        int j = tid >> 6, cc = tid & 63, ll = cc >> 2, c = cc & 3;
        float s = 0.f;
#pragma unroll
        for (int w = 0; w < 4; ++w) s += ((const float*)&colred4[w][j][ll])[c];
        hpartdst[((size_t)b * NT + tile) * DD + tid] = s;
    }
}

// ---------------------------------------------------------------------------
// Kernel 4: reduce spart partials, finalize Y1/Y2, Kabsch (fp64 Jacobi SVD).
// grid 16 (one per batch), 128 threads. HW-verified in round 3.
__global__ __launch_bounds__(128) void k_final(const float* __restrict__ spart,
                                               float* __restrict__ out) {
    int b = blockIdx.x;
    int tid = threadIdx.x;
    __shared__ float acc[2][40];
    if (tid < 80) {
        int p = tid / 40, j = tid % 40;
        const float* sp = spart + (size_t)(p * NB + b) * NT * 40 + j;
        float s = 0.f;
        for (int tile = 0; tile < NT; ++tile) s += sp[(size_t)tile * 40];
        acc[p][j] = s;
    }
    __syncthreads();
    __shared__ float Ys[2][KK][3];
    if (tid < 2 * KK * 3) {
        int p = tid / 30;
        int r = tid % 30;
        int k = r / 3;
        int c = r % 3;
        float val = acc[p][10 + c * 10 + k] / acc[p][k];
        Ys[p][k][c] = val;
        out[((size_t)(b * 3 + p) * KK + k) * 3 + c] = val;
    }
    __syncthreads();
    if (tid == 0) {
        double P[KK][3], Q[KK][3];
        double c1[3] = {0, 0, 0}, c2[3] = {0, 0, 0};
        for (int i = 0; i < KK; ++i)
            for (int c = 0; c < 3; ++c) {
                P[i][c] = (double)Ys[0][i][c];
                Q[i][c] = (double)Ys[1][i][c];
                c1[c] += P[i][c];
                c2[c] += Q[i][c];
            }
        for (int c = 0; c < 3; ++c) { c1[c] /= KK; c2[c] /= KK; }
        double A0[3][3];
        for (int a = 0; a < 3; ++a)
            for (int c = 0; c < 3; ++c) {
                double s = 0;
                for (int i = 0; i < KK; ++i) s += (P[i][a] - c1[a]) * (Q[i][c] - c2[c]);
                A0[a][c] = s;
            }
        double Bm[3][3], V[3][3];
        for (int a = 0; a < 3; ++a)
            for (int c = 0; c < 3; ++c) { Bm[a][c] = A0[a][c]; V[a][c] = (a == c) ? 1.0 : 0.0; }
        for (int sweep = 0; sweep < 16; ++sweep)
            for (int p = 0; p < 2; ++p)
                for (int q = p + 1; q < 3; ++q) {
                    double al = 0, be = 0, ga = 0;
                    for (int r = 0; r < 3; ++r) {
                        al += Bm[r][p] * Bm[r][p];
                        be += Bm[r][q] * Bm[r][q];
                        ga += Bm[r][p] * Bm[r][q];
                    }
                    if (fabs(ga) < 1e-300) continue;
                    double zeta = (be - al) / (2.0 * ga);
                    double t = copysign(1.0, zeta) / (fabs(zeta) + sqrt(1.0 + zeta * zeta));
                    double cs = 1.0 / sqrt(1.0 + t * t);
                    double sn = cs * t;
                    for (int r = 0; r < 3; ++r) {
                        double bp = Bm[r][p], bq = Bm[r][q];
                        Bm[r][p] = cs * bp - sn * bq;
                        Bm[r][q] = sn * bp + cs * bq;
                        double vp = V[r][p], vq = V[r][q];
                        V[r][p] = cs * vp - sn * vq;
                        V[r][q] = sn * vp + cs * vq;
                    }
                }
        double sig[3];
        for (int j = 0; j < 3; ++j) {
            sig[j] = sqrt(Bm[0][j] * Bm[0][j] + Bm[1][j] * Bm[1][j] + Bm[2][j] * Bm[2][j]);
            if (sig[j] < 1e-300) sig[j] = 1e-300;
        }
        int jmin = 0;
        if (sig[1] < sig[jmin]) jmin = 1;
        if (sig[2] < sig[jmin]) jmin = 2;
        // sign(det(U @ Vt)) == sign(det(A0))
        double det = A0[0][0] * (A0[1][1] * A0[2][2] - A0[1][2] * A0[2][1])
                   - A0[0][1] * (A0[1][0] * A0[2][2] - A0[1][2] * A0[2][0])
                   + A0[0][2] * (A0[1][0] * A0[2][1] - A0[1][1] * A0[2][0]);
        double sgn = (det >= 0.0) ? 1.0 : -1.0;
        double R[3][3];
        for (int a = 0; a < 3; ++a)
            for (int c = 0; c < 3; ++c) {
                double s = 0;
                for (int j = 0; j < 3; ++j) {
                    double dj = (j == jmin) ? sgn : 1.0;
                    s += dj * (Bm[a][j] / sig[j]) * V[c][j];
                }
                R[a][c] = s;
            }
        for (int i = 0; i < KK; ++i)
            for (int c = 0; c < 3; ++c) {
                double s = c2[c];
                for (int a = 0; a < 3; ++a) s += (P[i][a] - c1[a]) * R[a][c];
                out[((size_t)(b * 3 + 2) * KK + i) * 3 + c] = (float)s;
            }
    }
}

// ---------------------------------------------------------------------------
// Pipeline: 3 streaming passes (402 MB logical vs round 3's 536):
//   sum(H2) -> v1 -> scores1(H1)+foldsum(H1) -> v2 -> scores2(H2) -> final
// 6 launches, no memset, no atomics.
extern "C" void kernel_launch(void* const* d_in, const int* in_sizes, int n_in,
                              void* d_out, int out_size, void* d_ws, size_t ws_size,
                              hipStream_t stream) {
    const float* H1 = (const float*)d_in[0];
    const float* H2 = (const float*)d_in[1];
    const float* X1 = (const float*)d_in[2];
    const float* X2 = (const float*)d_in[3];
    const float* W1 = (const float*)d_in[4];
    const float* W2 = (const float*)d_in[5];
    float* out = (float*)d_out;
    float* ws = (float*)d_ws;
    float* hpart2 = ws;                      // 262144 floats
    float* hpart1 = ws + 262144;             // 262144 floats
    float* v1     = ws + 524288;             // 20480 floats
    float* v2     = ws + 544768;             // 20480 floats
    float* spart  = ws + 565248;             // [2][NB][NT][40] = 163840 floats
    float* sp1 = spart;
    float* sp2 = spart + (size_t)NB * NT * 40;

    hipLaunchKernelGGL(k_sum,            dim3(2048), dim3(256), 0, stream, H2, hpart2);
    hipLaunchKernelGGL(k_v,              dim3(160),  dim3(128), 0, stream, W1, hpart2, v1);
    hipLaunchKernelGGL((k_scores<true>), dim3(2048), dim3(256), 0, stream,
                       H1, X1, v1, sp1, hpart1);
    hipLaunchKernelGGL(k_v,              dim3(160),  dim3(128), 0, stream, W2, hpart1, v2);
    hipLaunchKernelGGL((k_scores<false>),dim3(2048), dim3(256), 0, stream,
                       H2, X2, v2, sp2, (float*)nullptr);
    hipLaunchKernelGGL(k_final,          dim3(16),   dim3(128), 0, stream, spart, out);
}